// Round 9
// baseline (425.443 us; speedup 1.0000x reference)
//
#include <hip/hip_runtime.h>
#include <hip/hip_bf16.h>
#include <stdint.h>

#define V 200000
#define E 600000
#define NB1 782          // ceil(V/256)

using bf16x8_t = __attribute__((ext_vector_type(8))) short;
using f32x4_t  = __attribute__((ext_vector_type(4))) float;

__device__ __forceinline__ unsigned short f2bf(float f) {
  __hip_bfloat16 h = __float2bfloat16(f);
  return *reinterpret_cast<unsigned short*>(&h);
}
__device__ __forceinline__ float bf_lo(unsigned d) { return __uint_as_float(d << 16); }
__device__ __forceinline__ float bf_hi(unsigned d) { return __uint_as_float(d & 0xffff0000u); }
__device__ __forceinline__ float bf2f(unsigned short s) {
  return __uint_as_float(((unsigned)s) << 16);
}

// ---------------------------------------------------------------------------
// prep_w2: fragment-linear weights; B operands = coalesced 1KB loads from L2.
//   o = ((kg*24 + cg)*64 + lane)*8 + e ;  W[c][k], c=cg*16+(lane&15),
//   k = kg*32+(lane>>4)*8+e.  c<256 -> w0 ; c>=256 -> w1.
// ---------------------------------------------------------------------------
__global__ void prep_w2(const float* __restrict__ w0, const float* __restrict__ w1,
                        unsigned short* __restrict__ Wb2) {
  int o = blockIdx.x * 256 + threadIdx.x;        // 0..98303
  int kg = o / 12288;
  int r  = o - kg * 12288;
  int cg = r >> 9;
  int r2 = r & 511;
  int lane = r2 >> 3, e = r2 & 7;
  int c = cg * 16 + (lane & 15);
  int k = kg * 32 + (lane >> 4) * 8 + e;
  float v = (c < 256) ? w0[c * 256 + k] : w1[(c - 256) * 256 + k];
  Wb2[o] = f2bf(v);
}

// ---------------------------------------------------------------------------
// Pass 1: w1b[V,128] = bf16(verts @ w1^T + b1).
// Round-3-proven dbuf skeleton: BM=64, 512 thr, A reg-staged fp32->bf16 into
// 16KB XOR-swizzled dbuf LDS; wave wv owns w1 frag 16+wv (cols wv*16..+16).
// ---------------------------------------------------------------------------
__global__ __launch_bounds__(512, 8) void gemm_w1(
    const float* __restrict__ verts, const unsigned short* __restrict__ Wb2,
    const float* __restrict__ w1_b, unsigned short* __restrict__ w1b)
{
  __shared__ __align__(16) unsigned short As[2][64 * 64];   // 16 KB

  const int tid  = threadIdx.x;
  const int lane = tid & 63;
  const int wv   = tid >> 6;            // 0..7 -> cols [wv*16, +16)
  const int mBase = blockIdx.x * 64;

  const int srow  = tid >> 3;           // 0..63
  const int skseg = tid & 7;
  const float* vsrc = verts + (size_t)(mBase + srow) * 256 + skseg * 8;
  const int sW = srow * 64 + ((skseg ^ (srow & 7)) * 8);

  f32x4_t acc[4];
  #pragma unroll
  for (int m = 0; m < 4; ++m) acc[m] = (f32x4_t){0.f, 0.f, 0.f, 0.f};

  auto Aload = [&](int kb, float4* a) {
    a[0] = *(const float4*)(vsrc + kb * 64);
    a[1] = *(const float4*)(vsrc + kb * 64 + 4);
  };
  auto Awrite = [&](int b, const float4* a) {
    union { unsigned short us[8]; uint4 q; } p;
    p.us[0]=f2bf(a[0].x); p.us[1]=f2bf(a[0].y); p.us[2]=f2bf(a[0].z); p.us[3]=f2bf(a[0].w);
    p.us[4]=f2bf(a[1].x); p.us[5]=f2bf(a[1].y); p.us[6]=f2bf(a[1].z); p.us[7]=f2bf(a[1].w);
    *(uint4*)&As[b][sW] = p.q;
  };
  auto compute = [&](int b, int kb) {
    #pragma unroll
    for (int kc = 0; kc < 2; ++kc) {
      int kg = kb * 2 + kc;
      bf16x8_t bfr = *(const bf16x8_t*)(Wb2 + (size_t)(kg * 24 + 16 + wv) * 512 + lane * 8);
      #pragma unroll
      for (int m = 0; m < 4; ++m) {
        int row = m * 16 + (lane & 15);
        int seg = (kc * 4 + (lane >> 4)) ^ (row & 7);
        bf16x8_t af = *(const bf16x8_t*)&As[b][row * 64 + seg * 8];
        acc[m] = __builtin_amdgcn_mfma_f32_16x16x32_bf16(af, bfr, acc[m], 0, 0, 0);
      }
    }
  };

  { float4 a0[2]; Aload(0, a0); Awrite(0, a0); }
  __syncthreads();

  int buf = 0;
  #pragma unroll
  for (int kb = 0; kb < 3; ++kb) {
    float4 an[2];
    Aload(kb + 1, an);          // issue early: latency hides under compute
    compute(buf, kb);
    Awrite(buf ^ 1, an);
    __syncthreads();
    buf ^= 1;
  }
  compute(buf, 3);

  const int l15 = lane & 15, lq = lane >> 4;
  int col = wv * 16 + l15;
  float bias = w1_b[col];
  #pragma unroll
  for (int m = 0; m < 4; ++m) {
    int rb = mBase + m * 16 + lq * 4;
    #pragma unroll
    for (int r = 0; r < 4; ++r)
      w1b[(size_t)(rb + r) * 128 + col] = f2bf(acc[m][r] + bias);
  }
}

// ---------------------------------------------------------------------------
// Pass 2: out[V,256] = verts @ w0^T + b0 + pad(segment_sum(w1b[adj])).
// Round-4/5 fused structure, LDS cut to ~33KB -> 4 blocks/CU (32 waves).
// Gather: wave owns 8 rows; 8-deep masked batches (adj padded) into packed
// bf16 nb LDS. Then dbuf GEMM K-loop; epilogue adds nb, single out write.
// ---------------------------------------------------------------------------
__global__ __launch_bounds__(512, 8) void gemm_w0_gather(
    const float* __restrict__ verts, const unsigned short* __restrict__ Wb2,
    const float* __restrict__ w0_b, const int* __restrict__ rowptr,
    const int* __restrict__ adj, const unsigned short* __restrict__ w1b,
    float* __restrict__ out)
{
  __shared__ __align__(16) unsigned short As[2][64 * 64];   // 16 KB
  __shared__ unsigned int nbu[64 * 65];                     // 16.6 KB
  __shared__ int rp[65];

  const int tid  = threadIdx.x;
  const int lane = tid & 63;
  const int wv   = tid >> 6;            // 0..7 -> cols [wv*32, +32)
  const int mBase = blockIdx.x * 64;

  const int srow  = tid >> 3;           // 0..63
  const int skseg = tid & 7;
  const float* vsrc = verts + (size_t)(mBase + srow) * 256 + skseg * 8;
  const int sW = srow * 64 + ((skseg ^ (srow & 7)) * 8);

  if (tid < 65) rp[tid] = rowptr[mBase + tid];
  __syncthreads();

  // ---- Gather: wave wv owns rows wv*8..+8; lane covers cols {2l, 2l+1} ----
  {
    const unsigned int* w1d = (const unsigned int*)w1b;   // 64 dwords per row
    #pragma unroll 1
    for (int rr = 0; rr < 8; ++rr) {
      int lrow = wv * 8 + rr;
      int s = rp[lrow], e = rp[lrow + 1];
      float g0 = 0.f, g1 = 0.f;
      for (int j = s; j < e; j += 8) {              // 8-deep batches, masked
        int u[8];
        #pragma unroll
        for (int t = 0; t < 8; ++t) u[t] = adj[j + t];        // pad-safe
        unsigned d[8];
        #pragma unroll
        for (int t = 0; t < 8; ++t) d[t] = w1d[(size_t)u[t] * 64 + lane];
        #pragma unroll
        for (int t = 0; t < 8; ++t) {
          float x0 = (j + t < e) ? bf_lo(d[t]) : 0.f;
          float x1 = (j + t < e) ? bf_hi(d[t]) : 0.f;
          g0 += x0; g1 += x1;
        }
      }
      nbu[lrow * 65 + lane] = (unsigned)f2bf(g0) | ((unsigned)f2bf(g1) << 16);
    }
  }

  f32x4_t acc[4][2];
  #pragma unroll
  for (int m = 0; m < 4; ++m)
    #pragma unroll
    for (int n = 0; n < 2; ++n)
      acc[m][n] = (f32x4_t){0.f, 0.f, 0.f, 0.f};

  auto Aload = [&](int kb, float4* a) {
    a[0] = *(const float4*)(vsrc + kb * 64);
    a[1] = *(const float4*)(vsrc + kb * 64 + 4);
  };
  auto Awrite = [&](int b, const float4* a) {
    union { unsigned short us[8]; uint4 q; } p;
    p.us[0]=f2bf(a[0].x); p.us[1]=f2bf(a[0].y); p.us[2]=f2bf(a[0].z); p.us[3]=f2bf(a[0].w);
    p.us[4]=f2bf(a[1].x); p.us[5]=f2bf(a[1].y); p.us[6]=f2bf(a[1].z); p.us[7]=f2bf(a[1].w);
    *(uint4*)&As[b][sW] = p.q;
  };
  auto compute = [&](int b, int kb) {
    #pragma unroll
    for (int kc = 0; kc < 2; ++kc) {
      int kg = kb * 2 + kc;
      bf16x8_t af[4];
      #pragma unroll
      for (int m = 0; m < 4; ++m) {
        int row = m * 16 + (lane & 15);
        int seg = (kc * 4 + (lane >> 4)) ^ (row & 7);
        af[m] = *(const bf16x8_t*)&As[b][row * 64 + seg * 8];
      }
      #pragma unroll
      for (int n = 0; n < 2; ++n) {
        int f = kg * 24 + wv * 2 + n;               // w0 region of Wb2
        bf16x8_t bfr = *(const bf16x8_t*)(Wb2 + (size_t)f * 512 + lane * 8);
        #pragma unroll
        for (int m = 0; m < 4; ++m)
          acc[m][n] = __builtin_amdgcn_mfma_f32_16x16x32_bf16(
              af[m], bfr, acc[m][n], 0, 0, 0);
      }
    }
  };

  { float4 a0[2]; Aload(0, a0); Awrite(0, a0); }
  __syncthreads();

  int buf = 0;
  #pragma unroll
  for (int kb = 0; kb < 3; ++kb) {
    float4 an[2];
    Aload(kb + 1, an);
    compute(buf, kb);
    Awrite(buf ^ 1, an);
    __syncthreads();
    buf ^= 1;
  }
  compute(buf, 3);

  // ---- Epilogue: out = acc + bias (+ nb for cols<128), single write ----
  const int l15 = lane & 15, lq = lane >> 4;
  const unsigned short* nb16 = (const unsigned short*)nbu;
  #pragma unroll
  for (int n = 0; n < 2; ++n) {
    int col = wv * 32 + n * 16 + l15;               // 0..255
    float bias = w0_b[col];
    #pragma unroll
    for (int m = 0; m < 4; ++m) {
      int rb = m * 16 + lq * 4;                     // local row
      #pragma unroll
      for (int r = 0; r < 4; ++r) {
        float v = acc[m][n][r] + bias;
        if (wv < 4) v += bf2f(nb16[(rb + r) * 130 + col]);   // wave-uniform
        out[(size_t)(mBase + rb + r) * 256 + col] = v;
      }
    }
  }
}

// ---------------------------------------------------------------------------
// CSR build
// ---------------------------------------------------------------------------
__global__ void count_deg(const int* __restrict__ edges, int* __restrict__ deg) {
  int i = blockIdx.x * blockDim.x + threadIdx.x;
  if (i >= 2 * E) return;
  int e = i >> 1, half = i & 1;
  atomicAdd(&deg[edges[2 * e + half]], 1);
}

__global__ void scan1(const int* __restrict__ deg, int* __restrict__ rowptr,
                      int* __restrict__ bsums) {
  __shared__ int sm[256];
  int i = blockIdx.x * 256 + threadIdx.x;
  int v = (i < V) ? deg[i] : 0;
  sm[threadIdx.x] = v;
  __syncthreads();
  for (int off = 1; off < 256; off <<= 1) {
    int t = (threadIdx.x >= off) ? sm[threadIdx.x - off] : 0;
    __syncthreads();
    sm[threadIdx.x] += t;
    __syncthreads();
  }
  if (i < V) rowptr[i] = sm[threadIdx.x] - v;
  if (threadIdx.x == 255) bsums[blockIdx.x] = sm[255];
}

__global__ void scan2(int* __restrict__ bsums) {
  __shared__ int sm[1024];
  int t = threadIdx.x;
  int v = (t < NB1) ? bsums[t] : 0;
  sm[t] = v;
  __syncthreads();
  for (int off = 1; off < 1024; off <<= 1) {
    int x = (t >= off) ? sm[t - off] : 0;
    __syncthreads();
    sm[t] += x;
    __syncthreads();
  }
  if (t < NB1) bsums[t] = sm[t] - v;
}

__global__ void scan3(int* __restrict__ rowptr, const int* __restrict__ bsums,
                      int* __restrict__ cursor) {
  int i = blockIdx.x * 256 + threadIdx.x;
  if (i < V) {
    int r = rowptr[i] + bsums[blockIdx.x];
    rowptr[i] = r;
    cursor[i] = r;
  }
  if (i == 0) rowptr[V] = 2 * E;
}

__global__ void fill_adj(const int* __restrict__ edges, int* __restrict__ cursor,
                         int* __restrict__ adj) {
  int i = blockIdx.x * blockDim.x + threadIdx.x;
  if (i >= 2 * E) return;
  int e = i >> 1, half = i & 1;
  int dst = edges[2 * e + half];
  int src = edges[2 * e + (half ^ 1)];
  adj[atomicAdd(&cursor[dst], 1)] = src;
}

// ---------------------------------------------------------------------------
extern "C" void kernel_launch(void* const* d_in, const int* in_sizes, int n_in,
                              void* d_out, int out_size, void* d_ws, size_t ws_size,
                              hipStream_t stream)
{
  const float* verts = (const float*)d_in[0];
  const int*   edges = (const int*)d_in[1];
  const float* w0_w  = (const float*)d_in[2];
  const float* w0_b  = (const float*)d_in[3];
  const float* w1_w  = (const float*)d_in[4];
  const float* w1_b  = (const float*)d_in[5];
  float* out = (float*)d_out;
  char*  ws  = (char*)d_ws;

  // workspace layout (bytes), total ~58.6 MB
  unsigned short* w1b = (unsigned short*)(ws);            // V*128*2 = 51,200,000
  int* rowptr = (int*)(ws + 51200000);                    // (V+1)*4
  int* cursor = (int*)(ws + 52000256);                    // V*4
  int* adj    = (int*)(ws + 52800256);                    // (2E+8)*4
  int* deg    = (int*)(ws + 57600288);                    // V*4
  int* bsums  = (int*)(ws + 58400288);                    // 1024*4
  unsigned short* Wb2 = (unsigned short*)(ws + 58404384); // 98304*2 = 196,608

  hipMemsetAsync(deg, 0, V * sizeof(int), stream);
  hipMemsetAsync(adj + 2 * E, 0, 8 * sizeof(int), stream);   // batch pad

  prep_w2<<<384, 256, 0, stream>>>(w0_w, w1_w, Wb2);

  count_deg<<<(2 * E + 255) / 256, 256, 0, stream>>>(edges, deg);
  scan1<<<NB1, 256, 0, stream>>>(deg, rowptr, bsums);
  scan2<<<1, 1024, 0, stream>>>(bsums);
  scan3<<<NB1, 256, 0, stream>>>(rowptr, bsums, cursor);
  fill_adj<<<(2 * E + 255) / 256, 256, 0, stream>>>(edges, cursor, adj);

  gemm_w1<<<V / 64, 512, 0, stream>>>(verts, Wb2, w1_b, w1b);

  gemm_w0_gather<<<V / 64, 512, 0, stream>>>(
      verts, Wb2, w0_b, rowptr, adj, w1b, out);
}